// Round 4
// baseline (214.038 us; speedup 1.0000x reference)
//
#include <hip/hip_runtime.h>
#include <stdint.h>

#define N_NODES 100000
#define N_EDGES 600000
#define FEAT 128
#define NTILES ((N_NODES + 63) / 64)     // 1563
#define GEMM_BLOCKS 512
#define EDGE_BLOCKS 2048

typedef __attribute__((ext_vector_type(8))) short short8;
typedef __attribute__((ext_vector_type(4))) float floatx4;

__device__ __forceinline__ unsigned f2bf_u(float f) {
    unsigned u = __builtin_bit_cast(unsigned, f);
    return (u + 0x7FFFu + ((u >> 16) & 1u)) >> 16;   // RNE, 16-bit result
}
__device__ __forceinline__ short f2bf(float f) { return (short)f2bf_u(f); }
__device__ __forceinline__ float bflo(int w) {
    return __builtin_bit_cast(float, (unsigned)w << 16);
}
__device__ __forceinline__ float bfhi(int w) {
    return __builtin_bit_cast(float, (unsigned)w & 0xFFFF0000u);
}

// Y[m] layout (permuted, 256 bf16 per row):
//   u-half position p in [0,128):  y[m*256 + p]       = (x[m] @ W1_top)[(p&7)*16 + (p>>3)]
//   v-half position p in [0,128):  y[m*256 + 128 + p] = (x[m] @ W1_bot)[(p&7)*16 + (p>>3)]
// pw[p] = { b1[j], W2[j] } with j = (p&7)*16 + (p>>3)

// wbt[n*128 + k] bf16 = (n<128) ? W1[k][n] : W1[128+k][n-128]; also builds pw.
__global__ void cvt_w_kernel(const float* __restrict__ w1, const float* __restrict__ b1,
                             const float* __restrict__ w2, short* __restrict__ wbt,
                             float2* __restrict__ pw) {
    int i = blockIdx.x * 256 + threadIdx.x;   // 32768
    int n = i >> 7, k = i & 127;
    float f = (n < FEAT) ? w1[k * FEAT + n] : w1[(FEAT + k) * FEAT + (n - FEAT)];
    wbt[i] = f2bf(f);
    if (i < 128) { int j = (i & 7) * 16 + (i >> 3); pw[i] = make_float2(b1[j], w2[j]); }
}

// Persistent GEMM: 512 blocks, each stages W once (64 KB bf16 LDS, conflict-free
// short8 writes) then loops over ~3 M-tiles of 64 nodes. No register pipeline
// (R3's cur/nxt pipeline spilled to scratch: WRITE_SIZE 123 MB vs 51 expected).
__global__ __launch_bounds__(256, 2) void node_gemm_kernel(
    const float* __restrict__ x, const short* __restrict__ wbt, short* __restrict__ y)
{
    __shared__ short lds_b[16 * 256 * 8];   // 64 KB, chunk-major [c=k/8][n][j=k%8]

    const int tid = threadIdx.x;
    // thread tid stages row n=tid: 16 chunks of 16 B, lane-contiguous LDS writes
    {
        const short8* src = (const short8*)(wbt + tid * 128);
#pragma unroll
        for (int c = 0; c < 16; ++c)
            *(short8*)(lds_b + (((c << 8) + tid) << 3)) = src[c];
    }
    __syncthreads();

    const int lane = tid & 63;
    const int wave = tid >> 6;
    const int nl = lane & 15;
    const int q  = lane >> 4;

    for (int t = blockIdx.x; t < NTILES; t += GEMM_BLOCKS) {
        int node = t * 64 + wave * 16 + nl;
        int nsrc = node < N_NODES ? node : N_NODES - 1;
        const float* bp = x + (size_t)nsrc * FEAT + q * 8;

        // A-fragment: lane holds A[m=nl][k=32s+8q+j]; convert immediately (low reg pressure)
        short8 a[4];
#pragma unroll
        for (int s = 0; s < 4; ++s) {
            float4 f0 = *(const float4*)(bp + s * 32);
            float4 f1 = *(const float4*)(bp + s * 32 + 4);
            short8 av;
            av[0] = f2bf(f0.x); av[1] = f2bf(f0.y); av[2] = f2bf(f0.z); av[3] = f2bf(f0.w);
            av[4] = f2bf(f1.x); av[5] = f2bf(f1.y); av[6] = f2bf(f1.z); av[7] = f2bf(f1.w);
            a[s] = av;
        }

        floatx4 acc[16];
#pragma unroll
        for (int nt = 0; nt < 16; ++nt) acc[nt] = (floatx4)(0.0f);

#pragma unroll
        for (int s = 0; s < 4; ++s) {
            const int crow = (s * 4 + q) << 8;   // chunk c = s*4+q
#pragma unroll
            for (int nt = 0; nt < 16; ++nt) {
                short8 bf = *(const short8*)(lds_b + ((crow + nt * 16 + nl) << 3));
                acc[nt] = __builtin_amdgcn_mfma_f32_16x16x32_bf16(a[s], bf, acc[nt], 0, 0, 0);
            }
        }

        // epilogue: lane nl packs 8 u-values / 8 v-values -> two 16 B stores per row
        const int m0 = t * 64 + wave * 16;
#pragma unroll
        for (int r = 0; r < 4; ++r) {
            int m = m0 + q * 4 + r;
            if (m < N_NODES) {
                int up[4], vp[4];
#pragma unroll
                for (int d = 0; d < 4; ++d) {
                    up[d] = (int)(f2bf_u(acc[2 * d][r])     | (f2bf_u(acc[2 * d + 1][r]) << 16));
                    vp[d] = (int)(f2bf_u(acc[8 + 2 * d][r]) | (f2bf_u(acc[9 + 2 * d][r]) << 16));
                }
                short* yr = y + (size_t)m * 256 + nl * 8;
                *(int4*)yr         = make_int4(up[0], up[1], up[2], up[3]);
                *(int4*)(yr + 128) = make_int4(vp[0], vp[1], vp[2], vp[3]);
            }
        }
    }
}

__device__ __forceinline__ float dotacc(int4 u, int4 v, const float2* pwr, int base, float p) {
    int uu[4] = {u.x, u.y, u.z, u.w};
    int vv[4] = {v.x, v.y, v.z, v.w};
#pragma unroll
    for (int d = 0; d < 4; ++d) {
        float h0 = bflo(uu[d]) + bflo(vv[d]) + pwr[base + 2 * d].x;
        float h1 = bfhi(uu[d]) + bfhi(vv[d]) + pwr[base + 2 * d + 1].x;
        p = fmaf(fmaxf(h0, 0.0f), pwr[base + 2 * d].y, p);
        p = fmaf(fmaxf(h1, 0.0f), pwr[base + 2 * d + 1].y, p);
    }
    return p;
}

// 8 lanes per edge, 16 features (32 B) per lane, unroll-2.
__global__ __launch_bounds__(256) void edge_kernel(
    const short* __restrict__ y, const int* __restrict__ eidx,
    const float2* __restrict__ pw, const float* __restrict__ b2,
    float* __restrict__ out)
{
    const int gt = blockIdx.x * 256 + threadIdx.x;
    const int l = gt & 7;
    const int g = gt >> 3;
    const int G = (EDGE_BLOCKS * 256) / 8;   // 65536 groups

    float2 pwr[16];
#pragma unroll
    for (int i = 0; i < 16; ++i) pwr[i] = pw[l * 16 + i];
    const float bias2 = b2[0];

    for (int e = g; e < N_EDGES; e += 2 * G) {
        int e2 = e + G;
        bool h2 = e2 < N_EDGES;
        int r1 = eidx[e];
        int c1 = eidx[N_EDGES + e];
        int r2 = h2 ? eidx[e2] : 0;
        int c2 = h2 ? eidx[N_EDGES + e2] : 0;

        const short* u1p = y + (size_t)r1 * 256 + l * 16;
        const short* v1p = y + (size_t)c1 * 256 + 128 + l * 16;
        const short* u2p = y + (size_t)r2 * 256 + l * 16;
        const short* v2p = y + (size_t)c2 * 256 + 128 + l * 16;
        int4 ua1 = *(const int4*)u1p, ub1 = *(const int4*)(u1p + 8);
        int4 va1 = *(const int4*)v1p, vb1 = *(const int4*)(v1p + 8);
        int4 ua2 = *(const int4*)u2p, ub2 = *(const int4*)(u2p + 8);
        int4 va2 = *(const int4*)v2p, vb2 = *(const int4*)(v2p + 8);

        float p1 = 0.0f, p2 = 0.0f;
        p1 = dotacc(ua1, va1, pwr, 0, p1);
        p1 = dotacc(ub1, vb1, pwr, 8, p1);
        p2 = dotacc(ua2, va2, pwr, 0, p2);
        p2 = dotacc(ub2, vb2, pwr, 8, p2);

        p1 += __shfl_xor(p1, 1);  p2 += __shfl_xor(p2, 1);
        p1 += __shfl_xor(p1, 2);  p2 += __shfl_xor(p2, 2);
        p1 += __shfl_xor(p1, 4);  p2 += __shfl_xor(p2, 4);

        if (l == 0) {
            out[e] = 1.0f / (1.0f + __expf(-(p1 + bias2)));
            if (h2) out[e2] = 1.0f / (1.0f + __expf(-(p2 + bias2)));
        }
    }
}

extern "C" void kernel_launch(void* const* d_in, const int* in_sizes, int n_in,
                              void* d_out, int out_size, void* d_ws, size_t ws_size,
                              hipStream_t stream) {
    const float* x  = (const float*)d_in[0];
    const int*   ei = (const int*)d_in[1];
    const float* W1 = (const float*)d_in[2];
    const float* b1 = (const float*)d_in[3];
    const float* W2 = (const float*)d_in[4];
    const float* b2 = (const float*)d_in[5];
    float* out = (float*)d_out;

    short*  ybf = (short*)d_ws;                              // 100000*256 shorts = 51.2 MB
    short*  wbt = ybf + (size_t)N_NODES * 256;               // 32768 shorts
    float2* pw  = (float2*)(wbt + 32768);                    // 128 float2

    cvt_w_kernel<<<32768 / 256, 256, 0, stream>>>(W1, b1, W2, wbt, pw);
    node_gemm_kernel<<<GEMM_BLOCKS, 256, 0, stream>>>(x, wbt, ybf);
    edge_kernel<<<EDGE_BLOCKS, 256, 0, stream>>>(ybf, ei, pw, b2, out);
}

// Round 6
// 172.729 us; speedup vs baseline: 1.2392x; 1.2392x over previous
//
#include <hip/hip_runtime.h>
#include <stdint.h>

#define N_NODES 100000
#define N_EDGES 600000
#define FEAT 128
#define NTILES16 (N_NODES / 16)          // 6250 (exact)
#define GEMM_BLOCKS 1024
#define EDGE_BLOCKS 2048

typedef __attribute__((ext_vector_type(8))) short short8;
typedef __attribute__((ext_vector_type(4))) float floatx4;

__device__ __forceinline__ unsigned f2bf_u(float f) {
    unsigned u = __builtin_bit_cast(unsigned, f);
    return (u + 0x7FFFu + ((u >> 16) & 1u)) >> 16;   // RNE, 16-bit result
}
__device__ __forceinline__ short f2bf(float f) { return (short)f2bf_u(f); }
__device__ __forceinline__ float bflo(int w) {
    return __builtin_bit_cast(float, (unsigned)w << 16);
}
__device__ __forceinline__ float bfhi(int w) {
    return __builtin_bit_cast(float, (unsigned)w & 0xFFFF0000u);
}
__device__ __forceinline__ unsigned pack_bf2(float a, float b) {
    return f2bf_u(a) | (f2bf_u(b) << 16);
}

// Y[m] row = 256 bf16, position p = w*64 + nl*4 + nt holds hidden-unit
// n(p) = (p>>6)*64 + (p&3)*16 + ((p>>2)&15)  (u-half p<128, v-half p>=128,
// same permutation in both halves). pw[p] = {b1[n(p)], W2[n(p)]} for p<128.

// wbt[n*128 + k] bf16 = (n<128) ? W1[k][n] : W1[128+k][n-128]
__global__ void cvt_w_kernel(const float* __restrict__ w1, const float* __restrict__ b1,
                             const float* __restrict__ w2, short* __restrict__ wbt,
                             float2* __restrict__ pw) {
    int i = blockIdx.x * 256 + threadIdx.x;   // 32768
    int n = i >> 7, k = i & 127;
    float f = (n < FEAT) ? w1[k * FEAT + n] : w1[(FEAT + k) * FEAT + (n - FEAT)];
    wbt[i] = f2bf(f);
    if (i < 128) {
        int j = ((i >> 6) << 6) + (i & 3) * 16 + ((i >> 2) & 15);
        pw[i] = make_float2(b1[j], w2[j]);
    }
}

// LDS-free GEMM: each wave owns a 64-column quarter, B-frags live in 64 VGPRs
// for the whole kernel. 4 waves/block share each 16-node tile (x hits L1).
__global__ __launch_bounds__(256, 2) void node_gemm_kernel(
    const float* __restrict__ x, const short* __restrict__ wbt, short* __restrict__ y)
{
    const int tid  = threadIdx.x;
    const int lane = tid & 63;
    const int w    = tid >> 6;     // wave id = n-quarter
    const int nl   = lane & 15;
    const int q    = lane >> 4;

    // B fragments: b[s*4+nt] = B[k=32s+8q+j][n=w*64+nt*16+nl], j=0..7
    short8 b[16];
#pragma unroll
    for (int s = 0; s < 4; ++s)
#pragma unroll
        for (int nt = 0; nt < 4; ++nt) {
            int n = w * 64 + nt * 16 + nl;
            b[s * 4 + nt] = *(const short8*)(wbt + n * 128 + s * 32 + q * 8);
        }

    for (int t = blockIdx.x; t < NTILES16; t += GEMM_BLOCKS) {
        const float* bp = x + (size_t)(t * 16 + nl) * FEAT + q * 8;

        // A-frag: lane holds A[m=nl][k=32s+8q+j]
        short8 a[4];
#pragma unroll
        for (int s = 0; s < 4; ++s) {
            float4 f0 = *(const float4*)(bp + s * 32);
            float4 f1 = *(const float4*)(bp + s * 32 + 4);
            int4 ai;
            ai.x = (int)pack_bf2(f0.x, f0.y);
            ai.y = (int)pack_bf2(f0.z, f0.w);
            ai.z = (int)pack_bf2(f1.x, f1.y);
            ai.w = (int)pack_bf2(f1.z, f1.w);
            a[s] = __builtin_bit_cast(short8, ai);
        }

        floatx4 acc[4];
#pragma unroll
        for (int nt = 0; nt < 4; ++nt) acc[nt] = (floatx4)(0.0f);

#pragma unroll
        for (int s = 0; s < 4; ++s)
#pragma unroll
            for (int nt = 0; nt < 4; ++nt)
                acc[nt] = __builtin_amdgcn_mfma_f32_16x16x32_bf16(a[s], b[s * 4 + nt], acc[nt], 0, 0, 0);

        // store: lane packs nt=0..3 -> 8 B at row position w*64 + nl*4
#pragma unroll
        for (int r = 0; r < 4; ++r) {
            int m = t * 16 + q * 4 + r;
            int2 pk;
            pk.x = (int)pack_bf2(acc[0][r], acc[1][r]);
            pk.y = (int)pack_bf2(acc[2][r], acc[3][r]);
            *(int2*)(y + (size_t)m * 256 + w * 64 + nl * 4) = pk;
        }
    }
}

__device__ __forceinline__ float dotacc(int4 u, int4 v, const float2* pwr, int base, float p) {
    int uu[4] = {u.x, u.y, u.z, u.w};
    int vv[4] = {v.x, v.y, v.z, v.w};
#pragma unroll
    for (int d = 0; d < 4; ++d) {
        float h0 = bflo(uu[d]) + bflo(vv[d]) + pwr[base + 2 * d].x;
        float h1 = bfhi(uu[d]) + bfhi(vv[d]) + pwr[base + 2 * d + 1].x;
        p = fmaf(fmaxf(h0, 0.0f), pwr[base + 2 * d].y, p);
        p = fmaf(fmaxf(h1, 0.0f), pwr[base + 2 * d + 1].y, p);
    }
    return p;
}

// 8 lanes per edge, 16 positions (32 B) per lane, unroll-2.
__global__ __launch_bounds__(256) void edge_kernel(
    const short* __restrict__ y, const int* __restrict__ eidx,
    const float2* __restrict__ pw, const float* __restrict__ b2,
    float* __restrict__ out)
{
    const int gt = blockIdx.x * 256 + threadIdx.x;
    const int l = gt & 7;
    const int g = gt >> 3;
    const int G = (EDGE_BLOCKS * 256) / 8;   // 65536 groups

    float2 pwr[16];
#pragma unroll
    for (int i = 0; i < 16; ++i) pwr[i] = pw[l * 16 + i];
    const float bias2 = b2[0];

    for (int e = g; e < N_EDGES; e += 2 * G) {
        int e2 = e + G;
        bool h2 = e2 < N_EDGES;
        int r1 = eidx[e];
        int c1 = eidx[N_EDGES + e];
        int r2 = h2 ? eidx[e2] : 0;
        int c2 = h2 ? eidx[N_EDGES + e2] : 0;

        const short* u1p = y + (size_t)r1 * 256 + l * 16;
        const short* v1p = y + (size_t)c1 * 256 + 128 + l * 16;
        const short* u2p = y + (size_t)r2 * 256 + l * 16;
        const short* v2p = y + (size_t)c2 * 256 + 128 + l * 16;
        int4 ua1 = *(const int4*)u1p, ub1 = *(const int4*)(u1p + 8);
        int4 va1 = *(const int4*)v1p, vb1 = *(const int4*)(v1p + 8);
        int4 ua2 = *(const int4*)u2p, ub2 = *(const int4*)(u2p + 8);
        int4 va2 = *(const int4*)v2p, vb2 = *(const int4*)(v2p + 8);

        float p1 = 0.0f, p2 = 0.0f;
        p1 = dotacc(ua1, va1, pwr, 0, p1);
        p1 = dotacc(ub1, vb1, pwr, 8, p1);
        p2 = dotacc(ua2, va2, pwr, 0, p2);
        p2 = dotacc(ub2, vb2, pwr, 8, p2);

        p1 += __shfl_xor(p1, 1);  p2 += __shfl_xor(p2, 1);
        p1 += __shfl_xor(p1, 2);  p2 += __shfl_xor(p2, 2);
        p1 += __shfl_xor(p1, 4);  p2 += __shfl_xor(p2, 4);

        if (l == 0) {
            out[e] = 1.0f / (1.0f + __expf(-(p1 + bias2)));
            if (h2) out[e2] = 1.0f / (1.0f + __expf(-(p2 + bias2)));
        }
    }
}

extern "C" void kernel_launch(void* const* d_in, const int* in_sizes, int n_in,
                              void* d_out, int out_size, void* d_ws, size_t ws_size,
                              hipStream_t stream) {
    const float* x  = (const float*)d_in[0];
    const int*   ei = (const int*)d_in[1];
    const float* W1 = (const float*)d_in[2];
    const float* b1 = (const float*)d_in[3];
    const float* W2 = (const float*)d_in[4];
    const float* b2 = (const float*)d_in[5];
    float* out = (float*)d_out;

    short*  ybf = (short*)d_ws;                              // 100000*256 shorts = 51.2 MB
    short*  wbt = ybf + (size_t)N_NODES * 256;               // 32768 shorts
    float2* pw  = (float2*)(wbt + 32768);                    // 128 float2

    cvt_w_kernel<<<32768 / 256, 256, 0, stream>>>(W1, b1, W2, wbt, pw);
    node_gemm_kernel<<<GEMM_BLOCKS, 256, 0, stream>>>(x, wbt, ybf);
    edge_kernel<<<EDGE_BLOCKS, 256, 0, stream>>>(ybf, ei, pw, b2, out);
}